// Round 1
// baseline (738.443 us; speedup 1.0000x reference)
//
#include <hip/hip_runtime.h>
#include <math.h>

// Problem constants (fixed by setup_inputs): x (8,64,384,384) fp32, params (8,2) fp32.
#define B_  8
#define C_  64
#define H_  384
#define W_  384

#define TX 64          // output tile width
#define TY 16          // output tile height
#define HALO 4         // max tap reach for k in {5..9} incl. even-k resize blend
#define SW (TX + 2*HALO)   // 72 staged cols
#define SH (TY + 2*HALO)   // 24 staged rows

__global__ __launch_bounds__(256) void gauss_blur_kernel(
    const float* __restrict__ x, const float* __restrict__ params,
    float* __restrict__ out)
{
    const int b    = blockIdx.z;
    const int c    = blockIdx.y;
    const int tile = blockIdx.x;          // 0..(6*24-1)
    const int ntx  = W_ / TX;             // 6
    const int tx0  = (tile % ntx) * TX;
    const int ty0  = (tile / ntx) * TY;

    // ---- per-batch params (computed redundantly per thread; trivial cost) ----
    const float p0 = params[2*b + 0];
    const float p1 = params[2*b + 1];
    const float k_int = truncf(p0);                       // torch .long() truncates toward 0
    const float s0 = 1.0f / (1.0f + expf(-k_int));        // sigmoid
    int k = (int)floorf(5.0f + 5.0f * s0);                // in {5..9}
    if (k < 5) k = 5;
    if (k > 9) k = 9;
    const float sigma = 0.5f + 4.5f * (1.0f / (1.0f + expf(-p1)));
    const int  pad  = k >> 1;
    const bool even = ((k & 1) == 0);

    // normalized 1D Gaussian: coords i - k//2, i in [0,k)
    float g[9];
    {
        const float inv2s2 = 1.0f / (2.0f * sigma * sigma);
        float S = 0.0f;
        for (int i = 0; i < 9; ++i) {
            float d = (float)(i - pad);
            float e = (i < k) ? expf(-d * d * inv2s2) : 0.0f;
            g[i] = e; S += e;
        }
        const float invS = 1.0f / S;
        for (int i = 0; i < 9; ++i) g[i] *= invS;
    }

    __shared__ float sIn[SH][SW];    // staged input tile + halo
    __shared__ float sTmp[SH][TX];   // after horizontal pass

    const size_t plane = (size_t)(b * C_ + c) * (size_t)(H_ * W_);
    const float* xp = x + plane;
    float*       op = out + plane;
    const int tid = threadIdx.x;

    // ---- stage input tile (zero-pad OOB) ----
    for (int li = tid; li < SH * SW; li += 256) {
        int r   = li / SW;
        int col = li - r * SW;
        int gr  = ty0 - HALO + r;
        int gc  = tx0 - HALO + col;
        float v = 0.0f;
        if (gr >= 0 && gr < H_ && gc >= 0 && gc < W_)
            v = xp[(size_t)gr * W_ + gc];
        sIn[r][col] = v;
    }
    __syncthreads();

    // ---- horizontal pass (+ horizontal resize blend when k even) ----
    // conv col w needs staged cols (w - pad + i), i in [0,k); staged col index = w - tx0 + HALO
    for (int li = tid; li < SH * TX; li += 256) {
        int r  = li >> 6;          // 0..23
        int xx = li & 63;          // 0..63
        int base = xx + HALO - pad;
        float a0 = 0.0f, a1 = 0.0f;
        // read k+1 values once; a0 = conv at col w, a1 = conv at col w+1
        float prevv = 0.0f;
        for (int t = 0; t <= k; ++t) {
            float v = sIn[r][base + t];
            if (t < k) a0 += g[t] * v;
            if (t > 0) a1 += g[t - 1] * v;
            prevv = v;
        }
        (void)prevv;
        float val = a0;
        if (even) {
            float fw = ((float)(tx0 + xx) + 0.5f) * (1.0f / (float)W_);
            val = a0 + fw * (a1 - a0);   // bilinear blend of cols w, w+1
        }
        sTmp[r][xx] = val;
    }
    __syncthreads();

    // ---- vertical pass (+ vertical resize blend when k even) ----
    for (int li = tid; li < TY * TX; li += 256) {
        int yy = li >> 6;          // 0..15
        int xx = li & 63;          // 0..63
        int base = yy + HALO - pad;
        float a0 = 0.0f, a1 = 0.0f;
        for (int t = 0; t <= k; ++t) {
            float v = sTmp[base + t][xx];
            if (t < k) a0 += g[t] * v;
            if (t > 0) a1 += g[t - 1] * v;
        }
        float val = a0;
        if (even) {
            float fh = ((float)(ty0 + yy) + 0.5f) * (1.0f / (float)H_);
            val = a0 + fh * (a1 - a0);
        }
        op[(size_t)(ty0 + yy) * W_ + (tx0 + xx)] = val;
    }
}

extern "C" void kernel_launch(void* const* d_in, const int* in_sizes, int n_in,
                              void* d_out, int out_size, void* d_ws, size_t ws_size,
                              hipStream_t stream) {
    const float* x      = (const float*)d_in[0];
    const float* params = (const float*)d_in[1];
    float* out          = (float*)d_out;

    dim3 grid((W_ / TX) * (H_ / TY), C_, B_);   // (144, 64, 8)
    dim3 block(256, 1, 1);
    gauss_blur_kernel<<<grid, block, 0, stream>>>(x, params, out);
}

// Round 2
// 487.881 us; speedup vs baseline: 1.5136x; 1.5136x over previous
//
#include <hip/hip_runtime.h>
#include <math.h>

// x: (8,64,384,384) fp32; params: (8,2) fp32.
#define B_  8
#define C_  64
#define H_  384
#define W_  384

#define TX   64              // output tile width
#define TY   32              // output tile height
#define HALO 4               // covers taps for all k in {5..9} incl. even-k resize blend
#define SW   (TX + 2*HALO)   // 72 staged cols (data)
#define SH   (TY + 2*HALO)   // 40 staged rows
#define SWP  76              // padded LDS stride for sIn  (16B-aligned, bank-spread)
#define TXP  68              // padded LDS stride for sTmp (16B-aligned, bank-spread)

template<int K>
__device__ __forceinline__ void process_tile(
    float (*sIn)[SWP], float (*sTmp)[TXP],
    float* __restrict__ op, int tx0, int ty0, float sigma, int tid)
{
    constexpr int  PAD  = K / 2;
    constexpr bool EVEN = ((K & 1) == 0);

    // normalized 1D Gaussian weights, fully in registers
    float g[K];
    {
        const float inv2s2 = 1.0f / (2.0f * sigma * sigma);
        float S = 0.0f;
        #pragma unroll
        for (int i = 0; i < K; ++i) {
            float d = (float)(i - PAD);
            g[i] = expf(-d * d * inv2s2);
            S += g[i];
        }
        const float invS = 1.0f / S;
        #pragma unroll
        for (int i = 0; i < K; ++i) g[i] *= invS;
    }

    // ---- horizontal pass: each task = (row r, 8-col group gx) ----
    // 40 rows x 8 groups = 320 tasks
    for (int li = tid; li < SH * 8; li += 256) {
        const int r  = li >> 3;
        const int g8 = (li & 7) * 8;
        float V[16];
        #pragma unroll
        for (int i = 0; i < 16; ++i) V[i] = sIn[r][g8 + i];   // 32B-aligned -> b128s
        #pragma unroll
        for (int j = 0; j < 8; ++j) {
            float a0 = 0.0f;
            #pragma unroll
            for (int t = 0; t < K; ++t) a0 += g[t] * V[j + 4 - PAD + t];
            float val = a0;
            if (EVEN) {
                float a1 = 0.0f;
                #pragma unroll
                for (int t = 0; t < K; ++t) a1 += g[t] * V[j + 5 - PAD + t];
                const float fw = ((float)(tx0 + g8 + j) + 0.5f) * (1.0f / (float)W_);
                val = a0 + fw * (a1 - a0);
            }
            sTmp[r][g8 + j] = val;
        }
    }
    __syncthreads();

    // ---- vertical pass: each task = (4-row group yg, col xx) ----
    // (TY/4)=8 groups x 64 cols = 512 tasks
    for (int li = tid; li < (TY / 4) * 64; li += 256) {
        const int yg = li >> 6;
        const int xx = li & 63;
        float U[12];
        #pragma unroll
        for (int i = 0; i < 12; ++i) U[i] = sTmp[yg * 4 + i][xx];
        #pragma unroll
        for (int j = 0; j < 4; ++j) {
            float a0 = 0.0f;
            #pragma unroll
            for (int t = 0; t < K; ++t) a0 += g[t] * U[j + 4 - PAD + t];
            float val = a0;
            if (EVEN) {
                float a1 = 0.0f;
                #pragma unroll
                for (int t = 0; t < K; ++t) a1 += g[t] * U[j + 5 - PAD + t];
                const float fh = ((float)(ty0 + yg * 4 + j) + 0.5f) * (1.0f / (float)H_);
                val = a0 + fh * (a1 - a0);
            }
            op[(size_t)(ty0 + yg * 4 + j) * W_ + (tx0 + xx)] = val;
        }
    }
}

__global__ __launch_bounds__(256) void gauss_blur_kernel(
    const float* __restrict__ x, const float* __restrict__ params,
    float* __restrict__ out)
{
    const int b    = blockIdx.z;
    const int c    = blockIdx.y;
    const int tile = blockIdx.x;          // 0..71
    const int ntx  = W_ / TX;             // 6
    const int tx0  = (tile % ntx) * TX;
    const int ty0  = (tile / ntx) * TY;

    // per-batch params (redundant per thread; trivial)
    const float p0 = params[2 * b + 0];
    const float p1 = params[2 * b + 1];
    const float k_int = truncf(p0);                       // torch .long() truncation
    const float s0 = 1.0f / (1.0f + expf(-k_int));
    int k = (int)floorf(5.0f + 5.0f * s0);                // {5..9}
    if (k < 5) k = 5;
    if (k > 9) k = 9;
    const float sigma = 0.5f + 4.5f * (1.0f / (1.0f + expf(-p1)));

    __shared__ float sIn[SH][SWP];
    __shared__ float sTmp[SH][TXP];

    const size_t plane = (size_t)(b * C_ + c) * (size_t)(H_ * W_);
    const float* xp = x + plane;
    float*       op = out + plane;
    const int tid = threadIdx.x;

    // ---- stage input tile as float4 (whole float4 is in- or out-of-bounds) ----
    // 40 rows x 18 float4 = 720 tasks
    for (int li = tid; li < SH * (SW / 4); li += 256) {
        const int r  = li / (SW / 4);
        const int c4 = li - r * (SW / 4);
        const int gr = ty0 - HALO + r;
        const int gc = tx0 - HALO + c4 * 4;
        float4 v = make_float4(0.f, 0.f, 0.f, 0.f);
        if (gr >= 0 && gr < H_ && gc >= 0 && gc < W_)
            v = *reinterpret_cast<const float4*>(xp + (size_t)gr * W_ + gc);
        *reinterpret_cast<float4*>(&sIn[r][c4 * 4]) = v;
    }
    __syncthreads();

    switch (k) {   // wave-uniform (k depends only on b)
        case 5:  process_tile<5>(sIn, sTmp, op, tx0, ty0, sigma, tid); break;
        case 6:  process_tile<6>(sIn, sTmp, op, tx0, ty0, sigma, tid); break;
        case 7:  process_tile<7>(sIn, sTmp, op, tx0, ty0, sigma, tid); break;
        case 8:  process_tile<8>(sIn, sTmp, op, tx0, ty0, sigma, tid); break;
        default: process_tile<9>(sIn, sTmp, op, tx0, ty0, sigma, tid); break;
    }
}

extern "C" void kernel_launch(void* const* d_in, const int* in_sizes, int n_in,
                              void* d_out, int out_size, void* d_ws, size_t ws_size,
                              hipStream_t stream) {
    const float* x      = (const float*)d_in[0];
    const float* params = (const float*)d_in[1];
    float* out          = (float*)d_out;

    dim3 grid((W_ / TX) * (H_ / TY), C_, B_);   // (72, 64, 8)
    dim3 block(256, 1, 1);
    gauss_blur_kernel<<<grid, block, 0, stream>>>(x, params, out);
}